// Round 12
// baseline (276.632 us; speedup 1.0000x reference)
//
#include <hip/hip_runtime.h>
#include <stdint.h>

// QuantizedLinear (BitNet ternary): out = x @ q^T + bias
// 256x256 bf16 MFMA GEMM, 8 waves (2M x 4N), BK=64, 128KiB dbuf LDS,
// T2 both-sides XOR swizzle (0 conflicts) + cross-phase k-half pipeline:
// frags register-double-buffered; ds_reads of phase p+1 issue before MFMA of
// phase p; lgkmcnt(12) counted wait; vmcnt(0) only drains tile-old staging.

#define M_DIM 8192
#define N_DIM 4096
#define K_DIM 4096
#define BM 256
#define BN 256
#define BK 64

typedef __attribute__((ext_vector_type(8))) short bf16x8;
typedef __attribute__((ext_vector_type(4))) float f32x4;

#define BAR() asm volatile("s_barrier" ::: "memory")
#define VMW0() asm volatile("s_waitcnt vmcnt(0)" ::: "memory")
#define SB0() __builtin_amdgcn_sched_barrier(0)
#define LGKM(n)                                             \
  do {                                                      \
    SB0();                                                  \
    asm volatile("s_waitcnt lgkmcnt(" #n ")" ::: "memory"); \
    SB0();                                                  \
  } while (0)
#define MFMA_(d, va, vb) \
  d = __builtin_amdgcn_mfma_f32_16x16x32_bf16(va, vb, d, 0, 0, 0)

// ---------- helpers ----------
__device__ __forceinline__ unsigned short f2bf_rne(float f) {
  unsigned int u = __float_as_uint(f);
  unsigned int r = (u + 0x7FFFu + ((u >> 16) & 1u)) >> 16;
  return (unsigned short)r;
}

__device__ __forceinline__ void load_lds16(const void* g, void* l) {
  __builtin_amdgcn_global_load_lds(
      (const __attribute__((address_space(1))) void*)g,
      (__attribute__((address_space(3))) void*)l,
      16, 0, 0);
}

// ---------- K1: per-block partial sums of |w| (deterministic) ----------
__global__ __launch_bounds__(256) void k_abs_partial(const float* __restrict__ w,
                                                     double* __restrict__ partial) {
  const int tid = threadIdx.x;
  const size_t base = (size_t)blockIdx.x * 8192 + (size_t)tid * 4;
  double s = 0.0;
#pragma unroll
  for (int it = 0; it < 8; ++it) {
    const float4 v = *reinterpret_cast<const float4*>(w + base + (size_t)it * 1024);
    s += (double)fabsf(v.x) + (double)fabsf(v.y) + (double)fabsf(v.z) + (double)fabsf(v.w);
  }
  __shared__ double sd[256];
  sd[tid] = s;
  __syncthreads();
  for (int off = 128; off > 0; off >>= 1) {
    if (tid < off) sd[tid] += sd[tid + off];
    __syncthreads();
  }
  if (tid == 0) partial[blockIdx.x] = sd[0];
}

// ---------- K2: finalize gamma (fp32 like numpy) ----------
__global__ __launch_bounds__(256) void k_abs_final(const double* __restrict__ partial,
                                                   float* __restrict__ gamma_out) {
  const int tid = threadIdx.x;
  double s = 0.0;
  for (int i = tid; i < 2048; i += 256) s += partial[i];
  __shared__ double sd[256];
  sd[tid] = s;
  __syncthreads();
  for (int off = 128; off > 0; off >>= 1) {
    if (tid < off) sd[tid] += sd[tid + off];
    __syncthreads();
  }
  if (tid == 0) {
    float g = (float)(sd[0] / 16777216.0);  // mean over 4096*4096
    gamma_out[0] = g + 1e-5f;
  }
}

// ---------- K3: quantize W -> ternary bf16 bits ----------
__global__ __launch_bounds__(256) void k_quant(const float* __restrict__ w,
                                               const float* __restrict__ gamma_p,
                                               unsigned short* __restrict__ qb) {
  const float g = gamma_p[0];
  const size_t n4 = (size_t)N_DIM * K_DIM / 4;
  const size_t stride = (size_t)gridDim.x * blockDim.x;
  for (size_t i = (size_t)blockIdx.x * blockDim.x + threadIdx.x; i < n4; i += stride) {
    const float4 v = reinterpret_cast<const float4*>(w)[i];
    ushort4 o;
    float r;
    r = rintf(v.x / g); o.x = (r >= 1.0f) ? 0x3F80 : ((r <= -1.0f) ? 0xBF80 : 0);
    r = rintf(v.y / g); o.y = (r >= 1.0f) ? 0x3F80 : ((r <= -1.0f) ? 0xBF80 : 0);
    r = rintf(v.z / g); o.z = (r >= 1.0f) ? 0x3F80 : ((r <= -1.0f) ? 0xBF80 : 0);
    r = rintf(v.w / g); o.w = (r >= 1.0f) ? 0x3F80 : ((r <= -1.0f) ? 0xBF80 : 0);
    reinterpret_cast<ushort4*>(qb)[i] = o;
  }
}

// ---------- K4: x fp32 -> bf16 ----------
__global__ __launch_bounds__(256) void k_cvt_x(const float* __restrict__ x,
                                               unsigned short* __restrict__ xb) {
  const size_t n4 = (size_t)M_DIM * K_DIM / 4;
  const size_t stride = (size_t)gridDim.x * blockDim.x;
  for (size_t i = (size_t)blockIdx.x * blockDim.x + threadIdx.x; i < n4; i += stride) {
    const float4 v = reinterpret_cast<const float4*>(x)[i];
    ushort4 o;
    o.x = f2bf_rne(v.x);
    o.y = f2bf_rne(v.y);
    o.z = f2bf_rne(v.z);
    o.w = f2bf_rne(v.w);
    reinterpret_cast<ushort4*>(xb)[i] = o;
  }
}

// ---------- K5: 256x256 cross-phase-pipelined bf16 MFMA GEMM ----------
// LDS swizzle (verified R9-R11, 0 conflicts): logical (row, cb) at physical
// byte row*128 + (cb ^ ((row&7)<<4)); inverse-swizzled global source
// (linear glds dest) + swizzled ds_read offset.
__global__ __launch_bounds__(512, 2) void k_gemm(const unsigned short* __restrict__ A,
                                                 const unsigned short* __restrict__ B,
                                                 const float* __restrict__ bias,
                                                 float* __restrict__ C) {
  __shared__ unsigned short lds[2][2][256][64];  // 128 KiB: [buf][op A=0/B=1][row][col]

  const int tid = threadIdx.x;
  const int wid = tid >> 6;   // 0..7
  const int lane = tid & 63;
  const int wm = wid >> 2;    // 0..1  (A row-half of this wave)
  const int wn = wid & 3;     // 0..3  (interleaved 16-col strip)
  const int l15 = lane & 15;
  const int l4 = lane >> 4;   // 0..3

  const int brow = blockIdx.y * BM;
  const int bcol = blockIdx.x * BN;

  // staging constants: seg s covers (row = s>>3, 16B slot = s&7) of a 128-row half
  const int s1 = 512 + tid;
  const int r0row = tid >> 3, r1row = s1 >> 3;
  const int r0col = ((((tid & 7) << 4) ^ ((r0row & 7) << 4)) >> 1);
  const int r1col = ((((s1 & 7) << 4) ^ ((r1row & 7) << 4)) >> 1);

  // ds_read swizzled column offsets (elements) for k-half 0/1
  const int xorv = (l15 & 7) << 4;
  const int ce0 = ((l4 * 16) ^ xorv) >> 1;
  const int ce1 = ((64 + l4 * 16) ^ xorv) >> 1;

#define STAGE(buf, op, half, kt)                                                      \
  do {                                                                                \
    const unsigned short* g0 =                                                        \
        ((op) ? B + (size_t)(bcol + (half)*128 + r0row) * K_DIM                       \
              : A + (size_t)(brow + (half)*128 + r0row) * K_DIM) + (kt)*64 + r0col;   \
    load_lds16(g0, (char*)&lds[buf][op][(half)*128][0] + (size_t)(wid * 64) * 16);    \
    const unsigned short* g1 =                                                        \
        ((op) ? B + (size_t)(bcol + (half)*128 + r1row) * K_DIM                       \
              : A + (size_t)(brow + (half)*128 + r1row) * K_DIM) + (kt)*64 + r1col;   \
    load_lds16(g1, (char*)&lds[buf][op][(half)*128][0] + (size_t)(512 + wid * 64) * 16); \
  } while (0)
#define STAGE_ALL(buf, kt)  \
  do {                      \
    STAGE(buf, 0, 0, kt);   \
    STAGE(buf, 0, 1, kt);   \
    STAGE(buf, 1, 0, kt);   \
    STAGE(buf, 1, 1, kt);   \
  } while (0)

  // 12 ds_read_b128: 8 A-frags + 4 B-frags of one k-half from buffer `buf`
#define READ_SET(AR, BR, buf, ce)                                              \
  do {                                                                         \
    _Pragma("unroll") for (int i = 0; i < 8; ++i)                              \
      AR[i] = *reinterpret_cast<const bf16x8*>(                                \
          &lds[buf][0][0][0] + (size_t)(wm * 128 + i * 16 + l15) * 64 + (ce)); \
    _Pragma("unroll") for (int p = 0; p < 4; ++p)                              \
      BR[p] = *reinterpret_cast<const bf16x8*>(                                \
          &lds[buf][1][0][0] + (size_t)(p * 64 + wn * 16 + l15) * 64 + (ce));  \
    SB0();                                                                     \
  } while (0)

  // 32 MFMA on one k-half fragment set
#define MFMA32(AR, BR)                                          \
  do {                                                          \
    __builtin_amdgcn_s_setprio(1);                              \
    _Pragma("unroll") for (int i = 0; i < 8; ++i)               \
      _Pragma("unroll") for (int p = 0; p < 4; ++p)             \
        MFMA_(acc[i][p], AR[i], BR[p]);                         \
    __builtin_amdgcn_s_setprio(0);                              \
  } while (0)

  f32x4 acc[8][4];
#pragma unroll
  for (int i = 0; i < 8; ++i)
#pragma unroll
    for (int p = 0; p < 4; ++p)
#pragma unroll
      for (int e = 0; e < 4; ++e) acc[i][p][e] = 0.0f;

  bf16x8 A0[8], B0[4], A1[8], B1[4];

  // prologue: stage tile0 -> buf0, tile1 -> buf1
  STAGE_ALL(0, 0);
  STAGE_ALL(1, 1);
  asm volatile("s_waitcnt vmcnt(8)" ::: "memory");  // tile0 landed; tile1 in flight
  BAR();
  READ_SET(A0, B0, 0, ce0);  // tile0 k-half0 -> setA

  int cur = 0;
  for (int t = 0; t < 64; ++t) {
    const int nbuf = cur ^ 1;
    // ---- phase A: MFMA k-half0 (setA) ; setB reads in flight under it ----
    READ_SET(A1, B1, cur, ce1);  // tile t k-half1 -> setB (12 ds, newest)
    LGKM(12);                    // setA complete (oldest 12)
    MFMA32(A0, B0);
    LGKM(0);                     // setB complete; all reads of buf[cur] done
    VMW0();                      // tile t+1 staging (issued a full tile ago) landed
    BAR();                       // publish buf[nbuf]; buf[cur] free for overwrite
    // ---- phase B: MFMA k-half1 (setB) ; next-tile k0 reads + staging under it ----
    if (t < 63) READ_SET(A0, B0, nbuf, ce0);  // tile t+1 k-half0 -> setA
    if (t < 62) STAGE_ALL(cur, t + 2);        // stage tile t+2 into vacated buf
    MFMA32(A1, B1);              // no wait: setB drained before the barrier
    cur = nbuf;
  }

  // ---- epilogue: C/D layout col=lane&15, row=(lane>>4)*4+j ----
  float bi[4];
#pragma unroll
  for (int p = 0; p < 4; ++p) bi[p] = bias[bcol + p * 64 + wn * 16 + l15];
#pragma unroll
  for (int i = 0; i < 8; ++i) {
#pragma unroll
    for (int j = 0; j < 4; ++j) {
      const int row = brow + wm * 128 + i * 16 + l4 * 4 + j;
      float* crow = C + (size_t)row * N_DIM + bcol + wn * 16 + l15;
#pragma unroll
      for (int p = 0; p < 4; ++p) crow[p * 64] = acc[i][p][j] + bi[p];
    }
  }
#undef STAGE
#undef STAGE_ALL
#undef READ_SET
#undef MFMA32
}

extern "C" void kernel_launch(void* const* d_in, const int* in_sizes, int n_in,
                              void* d_out, int out_size, void* d_ws, size_t ws_size,
                              hipStream_t stream) {
  (void)in_sizes; (void)n_in; (void)out_size; (void)ws_size;
  const float* x = (const float*)d_in[0];
  const float* w = (const float*)d_in[1];
  const float* bias = (const float*)d_in[2];
  float* out = (float*)d_out;

  char* ws = (char*)d_ws;
  unsigned short* xb = (unsigned short*)ws;                                  // 64 MB
  unsigned short* qb = (unsigned short*)(ws + (size_t)M_DIM * K_DIM * 2);    // 32 MB
  double* partial = (double*)(ws + (size_t)M_DIM * K_DIM * 2 + (size_t)N_DIM * K_DIM * 2);
  float* gamma = (float*)(partial + 2048);

  k_abs_partial<<<2048, 256, 0, stream>>>(w, partial);
  k_abs_final<<<1, 256, 0, stream>>>(partial, gamma);
  k_quant<<<2048, 256, 0, stream>>>(w, gamma, qb);
  k_cvt_x<<<2048, 256, 0, stream>>>(x, xb);

  dim3 grid(N_DIM / BN, M_DIM / BM);
  k_gemm<<<grid, 512, 0, stream>>>(xb, qb, bias, out);
}

// Round 13
// 199.158 us; speedup vs baseline: 1.3890x; 1.3890x over previous
//
#include <hip/hip_runtime.h>
#include <stdint.h>

// QuantizedLinear (BitNet ternary): out = x @ q^T + bias
// INT8 path: ternary weights exact in i8; x quantized per-row to i8
// (s_r = rowmax/127), dequant + bias in fp32 epilogue.
// 256x256 i8 MFMA GEMM (mfma_i32_16x16x64_i8), 8 waves (2M x 4N), BK=64,
// 64KiB dbuf LDS, 2-way-free XOR swizzle, 2-tile register pipeline with
// counted lgkmcnt(12) and tile-distance vmcnt drains.

#define M_DIM 8192
#define N_DIM 4096
#define K_DIM 4096
#define BM 256
#define BN 256
#define BK 64

typedef __attribute__((ext_vector_type(4))) int vi4;

#define BAR() asm volatile("s_barrier" ::: "memory")
#define VMW0() asm volatile("s_waitcnt vmcnt(0)" ::: "memory")
#define VMW4() asm volatile("s_waitcnt vmcnt(4)" ::: "memory")
#define SB0() __builtin_amdgcn_sched_barrier(0)
#define LGKM(n)                                             \
  do {                                                      \
    SB0();                                                  \
    asm volatile("s_waitcnt lgkmcnt(" #n ")" ::: "memory"); \
    SB0();                                                  \
  } while (0)

__device__ __forceinline__ void load_lds16(const void* g, void* l) {
  __builtin_amdgcn_global_load_lds(
      (const __attribute__((address_space(1))) void*)g,
      (__attribute__((address_space(3))) void*)l,
      16, 0, 0);
}

// ---------- K1: per-block partial sums of |w| (deterministic) ----------
__global__ __launch_bounds__(256) void k_abs_partial(const float* __restrict__ w,
                                                     double* __restrict__ partial) {
  const int tid = threadIdx.x;
  const size_t base = (size_t)blockIdx.x * 8192 + (size_t)tid * 4;
  double s = 0.0;
#pragma unroll
  for (int it = 0; it < 8; ++it) {
    const float4 v = *reinterpret_cast<const float4*>(w + base + (size_t)it * 1024);
    s += (double)fabsf(v.x) + (double)fabsf(v.y) + (double)fabsf(v.z) + (double)fabsf(v.w);
  }
  __shared__ double sd[256];
  sd[tid] = s;
  __syncthreads();
  for (int off = 128; off > 0; off >>= 1) {
    if (tid < off) sd[tid] += sd[tid + off];
    __syncthreads();
  }
  if (tid == 0) partial[blockIdx.x] = sd[0];
}

// ---------- K2: finalize gamma (fp32 like numpy) ----------
__global__ __launch_bounds__(256) void k_abs_final(const double* __restrict__ partial,
                                                   float* __restrict__ gamma_out) {
  const int tid = threadIdx.x;
  double s = 0.0;
  for (int i = tid; i < 2048; i += 256) s += partial[i];
  __shared__ double sd[256];
  sd[tid] = s;
  __syncthreads();
  for (int off = 128; off > 0; off >>= 1) {
    if (tid < off) sd[tid] += sd[tid + off];
    __syncthreads();
  }
  if (tid == 0) {
    float g = (float)(sd[0] / 16777216.0);  // mean over 4096*4096
    gamma_out[0] = g + 1e-5f;
  }
}

// ---------- K3: quantize W -> ternary int8 ----------
__global__ __launch_bounds__(256) void k_quant(const float* __restrict__ w,
                                               const float* __restrict__ gamma_p,
                                               int* __restrict__ qb) {
  const float g = gamma_p[0];
  const size_t n4 = (size_t)N_DIM * K_DIM / 4;
  const size_t stride = (size_t)gridDim.x * blockDim.x;
  for (size_t i = (size_t)blockIdx.x * blockDim.x + threadIdx.x; i < n4; i += stride) {
    const float4 v = reinterpret_cast<const float4*>(w)[i];
    float r;
    int a, b, c, d;
    r = rintf(v.x / g); a = (r >= 1.0f) ? 1 : ((r <= -1.0f) ? -1 : 0);
    r = rintf(v.y / g); b = (r >= 1.0f) ? 1 : ((r <= -1.0f) ? -1 : 0);
    r = rintf(v.z / g); c = (r >= 1.0f) ? 1 : ((r <= -1.0f) ? -1 : 0);
    r = rintf(v.w / g); d = (r >= 1.0f) ? 1 : ((r <= -1.0f) ? -1 : 0);
    qb[i] = (a & 0xff) | ((b & 0xff) << 8) | ((c & 0xff) << 16) | ((d & 0xff) << 24);
  }
}

// ---------- K4: x fp32 -> per-row-scaled int8 ----------
__global__ __launch_bounds__(256) void k_quant_x(const float* __restrict__ x,
                                                 signed char* __restrict__ xq,
                                                 float* __restrict__ xs) {
  const int row = blockIdx.x;  // 8192
  const int tid = threadIdx.x;
  const float* xr = x + (size_t)row * K_DIM;
  float4 v[4];
  float am = 0.0f;
#pragma unroll
  for (int i = 0; i < 4; ++i) {
    v[i] = reinterpret_cast<const float4*>(xr)[tid * 4 + i];
    am = fmaxf(am, fmaxf(fmaxf(fabsf(v[i].x), fabsf(v[i].y)),
                         fmaxf(fabsf(v[i].z), fabsf(v[i].w))));
  }
  for (int off = 32; off > 0; off >>= 1) am = fmaxf(am, __shfl_down(am, off));
  __shared__ float sm[4];
  if ((tid & 63) == 0) sm[tid >> 6] = am;
  __syncthreads();
  const float bm = fmaxf(fmaxf(fmaxf(sm[0], sm[1]), fmaxf(sm[2], sm[3])), 1e-20f);
  if (tid == 0) xs[row] = bm / 127.0f;
  const float inv = 127.0f / bm;
  union { signed char c[16]; int4 q; } u;
#pragma unroll
  for (int i = 0; i < 4; ++i) {
    u.c[i * 4 + 0] = (signed char)(int)rintf(v[i].x * inv);
    u.c[i * 4 + 1] = (signed char)(int)rintf(v[i].y * inv);
    u.c[i * 4 + 2] = (signed char)(int)rintf(v[i].z * inv);
    u.c[i * 4 + 3] = (signed char)(int)rintf(v[i].w * inv);
  }
  *reinterpret_cast<int4*>(xq + (size_t)row * K_DIM + tid * 16) = u.q;
}

// ---------- K5: 256x256 i8 MFMA GEMM ----------
// i8 LDS swizzle: 64B rows = 4x16B slots; logical slot c at phys slot
// c ^ ((row>>1)&3). Inverse-swizzled global source (linear glds dest) +
// swizzled ds_read -> 2-way bank aliasing (free).
__global__ __launch_bounds__(512, 2) void k_gemm(const signed char* __restrict__ Aq,
                                                 const signed char* __restrict__ Bq,
                                                 const float* __restrict__ xs,
                                                 const float* __restrict__ bias,
                                                 float* __restrict__ C) {
  __shared__ unsigned char lds[2][2][256][64];  // 64 KiB: [buf][op A=0/B=1][row][col]

  const int tid = threadIdx.x;
  const int wid = tid >> 6;   // 0..7
  const int lane = tid & 63;
  const int wm = wid >> 2;    // 0..1
  const int wn = wid & 3;     // 0..3
  const int l15 = lane & 15;
  const int l4 = lane >> 4;   // 0..3

  const int brow = blockIdx.y * BM;
  const int bcol = blockIdx.x * BN;

  // staging: lane covers (row = wid*16 + lane>>2, slot = lane&3) of a 128-row half
  const int srow = wid * 16 + (lane >> 2);
  const int scol = ((lane & 3) ^ ((lane >> 3) & 3)) << 4;  // inverse-swizzled src byte
  // ds_read: phys slot = l4 ^ ((row>>1)&3); row ≡ l15 (mod 8)
  const int rdoff = ((l4 ^ ((l15 >> 1) & 3)) << 4);

#define STAGE1(buf, op, half, kt)                                                  \
  do {                                                                             \
    const signed char* g =                                                         \
        ((op) ? Bq + (size_t)(bcol + (half)*128 + srow) * K_DIM                    \
              : Aq + (size_t)(brow + (half)*128 + srow) * K_DIM) + (kt)*64 + scol; \
    load_lds16(g, (char*)&lds[buf][op][(half)*128][0] + (size_t)wid * 1024);       \
  } while (0)
#define STAGE_ALL(buf, kt)       \
  do {                           \
    STAGE1(buf, 0, 0, kt);       \
    STAGE1(buf, 0, 1, kt);       \
    STAGE1(buf, 1, 0, kt);       \
    STAGE1(buf, 1, 1, kt);       \
  } while (0)

  // 12 ds_read_b128: 8 A-frags + 4 B-frags (full K=64 in one step)
#define READ_SET(AR, BR, buf)                                                     \
  do {                                                                            \
    _Pragma("unroll") for (int i = 0; i < 8; ++i)                                 \
      AR[i] = *reinterpret_cast<const vi4*>(                                      \
          &lds[buf][0][0][0] + (size_t)(wm * 128 + i * 16 + l15) * 64 + rdoff);   \
    _Pragma("unroll") for (int p = 0; p < 4; ++p)                                 \
      BR[p] = *reinterpret_cast<const vi4*>(                                      \
          &lds[buf][1][0][0] + (size_t)(p * 64 + wn * 16 + l15) * 64 + rdoff);    \
    SB0();                                                                        \
  } while (0)

#define MFMA32(AR, BR)                                                            \
  do {                                                                            \
    __builtin_amdgcn_s_setprio(1);                                                \
    _Pragma("unroll") for (int i = 0; i < 8; ++i)                                 \
      _Pragma("unroll") for (int p = 0; p < 4; ++p)                               \
        acc[i][p] = __builtin_amdgcn_mfma_i32_16x16x64_i8(AR[i], BR[p],           \
                                                          acc[i][p], 0, 0, 0);    \
    __builtin_amdgcn_s_setprio(0);                                                \
  } while (0)

  vi4 acc[8][4];
#pragma unroll
  for (int i = 0; i < 8; ++i)
#pragma unroll
    for (int p = 0; p < 4; ++p)
#pragma unroll
      for (int e = 0; e < 4; ++e) acc[i][p][e] = 0;

  vi4 Aa[8], Ba[4], Ab[8], Bb[4];

  // prologue: tile0 -> buf0, tile1 -> buf1
  STAGE_ALL(0, 0);
  STAGE_ALL(1, 1);
  VMW4();  // tile0 landed; tile1 in flight
  BAR();
  READ_SET(Aa, Ba, 0);  // tile0 frags

  // steady state, 2 tiles per iteration (tiles 0..61 in loop, 62/63 in tail)
  for (int tp = 0; tp < 31; ++tp) {
    const int t = 2 * tp;
    // tile t (buf0): prefetch tile t+1 frags, stage t+2
    VMW0();                 // tile t+1 staging landed (issued ~1 tile ago)
    BAR();                  // publish buf1 = tile t+1
    READ_SET(Ab, Bb, 1);
    LGKM(12);               // Aa/Ba (tile t) complete
    STAGE_ALL(0, t + 2);    // safe: buf0 reads drained for this wave
    MFMA32(Aa, Ba);
    // tile t+1 (buf1): prefetch tile t+2 frags, stage t+3
    VMW0();
    BAR();                  // publish buf0 = tile t+2
    READ_SET(Aa, Ba, 0);
    LGKM(12);               // Ab/Bb (tile t+1) complete
    STAGE_ALL(1, t + 3);
    MFMA32(Ab, Bb);
  }
  // tile 62 (buf0)
  VMW0();
  BAR();                    // publish buf1 = tile 63
  READ_SET(Ab, Bb, 1);
  LGKM(12);
  MFMA32(Aa, Ba);
  // tile 63 (buf1)
  LGKM(0);
  MFMA32(Ab, Bb);

  // ---- epilogue: C/D layout col=lane&15, row=(lane>>4)*4+j; dequant + bias ----
  float bi[4];
#pragma unroll
  for (int p = 0; p < 4; ++p) bi[p] = bias[bcol + p * 64 + wn * 16 + l15];
#pragma unroll
  for (int i = 0; i < 8; ++i) {
#pragma unroll
    for (int j = 0; j < 4; ++j) {
      const int row = brow + wm * 128 + i * 16 + l4 * 4 + j;
      const float sc = xs[row];
      float* crow = C + (size_t)row * N_DIM + bcol + wn * 16 + l15;
#pragma unroll
      for (int p = 0; p < 4; ++p) crow[p * 64] = (float)acc[i][p][j] * sc + bi[p];
    }
  }
#undef STAGE1
#undef STAGE_ALL
#undef READ_SET
#undef MFMA32
}

extern "C" void kernel_launch(void* const* d_in, const int* in_sizes, int n_in,
                              void* d_out, int out_size, void* d_ws, size_t ws_size,
                              hipStream_t stream) {
  (void)in_sizes; (void)n_in; (void)out_size; (void)ws_size;
  const float* x = (const float*)d_in[0];
  const float* w = (const float*)d_in[1];
  const float* bias = (const float*)d_in[2];
  float* out = (float*)d_out;

  char* ws = (char*)d_ws;
  signed char* xq = (signed char*)ws;                                   // 32 MB
  signed char* qb = (signed char*)(ws + (size_t)M_DIM * K_DIM);         // 16 MB
  float* xs = (float*)(ws + (size_t)M_DIM * K_DIM + (size_t)N_DIM * K_DIM);  // 32 KB
  double* partial = (double*)((char*)xs + M_DIM * sizeof(float));
  float* gamma = (float*)(partial + 2048);

  k_abs_partial<<<2048, 256, 0, stream>>>(w, partial);
  k_abs_final<<<1, 256, 0, stream>>>(partial, gamma);
  k_quant<<<2048, 256, 0, stream>>>(w, gamma, (int*)qb);
  k_quant_x<<<M_DIM, 256, 0, stream>>>(x, xq, xs);

  dim3 grid(N_DIM / BN, M_DIM / BM);
  k_gemm<<<grid, 512, 0, stream>>>(xq, qb, xs, bias, out);
}